// Round 10
// baseline (178.070 us; speedup 1.0000x reference)
//
#include <hip/hip_runtime.h>
#include <math.h>

// y_t = clamp(y_{t-1}, x_t, x_t+1): play operator as associative clamp-scan.
// compose(l, r) = "apply l first, then r". min/max/med3-only => exact =>
// any regrouping is bit-identical (deterministic).
//
// COLLAPSE PROPERTY: composed windows are contracting and width-0 is
// absorbing. Block 0's aggregate is width-0 (element 0 is the constant p0),
// and for N(0,1) data almost every block's aggregate is width-0 too. Hence a
// single-pass scan where each block only needs predecessor AGGREGATES (no
// prefix chain): publish own aggregate, then walk back composing aggregates
// until the suffix collapses (typical depth ~1). Input read once, output
// written once (128 MB compulsory).

#define TPB 256
#define EPT 16
#define EPB (TPB * EPT)   // 4096 elements per block -> nb = 4097 for T=2^24
#define LPAD 257          // LDS transpose pitch (words)

struct Pair { float a, b; };

__device__ __forceinline__ float med3f(float x, float lo, float hi) {
    return __builtin_amdgcn_fmed3f(x, lo, hi);   // clamp(x, lo, hi), lo<=hi
}
__device__ __forceinline__ Pair compose(Pair l, Pair r) {
    Pair o; o.a = med3f(l.a, r.a, r.b); o.b = med3f(l.b, r.a, r.b); return o;
}
__device__ __forceinline__ Pair ident() {
    Pair p; p.a = -INFINITY; p.b = INFINITY; return p;
}

__global__ __launch_bounds__(TPB)
void k_fused(const float* __restrict__ in, const float* __restrict__ kptr,
             int* counter, int* flags, float* agg_a, float* agg_b,
             float* __restrict__ out, int n) {
    __shared__ int   svid;
    __shared__ Pair  wS[TPB / 64];
    __shared__ float sY;
    __shared__ float xpose[EPT * LPAD];

    // dynamic block id in dispatch-start order (lookback forward progress)
    if (threadIdx.x == 0)
        svid = __hip_atomic_fetch_add(counter, 1, __ATOMIC_RELAXED,
                                      __HIP_MEMORY_SCOPE_AGENT);
    __syncthreads();
    const int vid  = svid;
    const int tid  = threadIdx.x, lane = tid & 63, wid = tid >> 6;
    const int tile0 = vid * EPB;
    const int base  = tile0 + tid * EPT;
    const float k   = kptr[0];
    const bool blockFull = (tile0 + EPB <= n);   // uniform across block

    // ---- local chain: per-element thread-local inclusive windows ----------
    float ta[EPT], tb[EPT];                      // static indexing only
    {
        float a = -INFINITY, b = INFINITY;
        if (blockFull) {
            #pragma unroll
            for (int v = 0; v < EPT / 4; ++v) {
                float4 f = reinterpret_cast<const float4*>(in + base)[v];
                float xv[4] = {f.x, f.y, f.z, f.w};
                #pragma unroll
                for (int jj = 0; jj < 4; ++jj) {
                    float lo = xv[jj] * k, hi = lo + 1.0f;
                    if (v == 0 && jj == 0 && base == 0) { lo = xv[0]; hi = xv[0]; }
                    a = med3f(a, lo, hi);
                    b = med3f(b, lo, hi);
                    ta[4*v+jj] = a; tb[4*v+jj] = b;
                }
            }
        } else {
            #pragma unroll
            for (int j = 0; j < EPT; ++j) {
                if (base + j < n) {
                    float x = in[base + j];
                    float lo = x * k, hi = lo + 1.0f;
                    if (j == 0 && base == 0) { lo = x; hi = x; }
                    a = med3f(a, lo, hi);
                    b = med3f(b, lo, hi);
                }
                ta[j] = a; tb[j] = b;
            }
        }
    }

    // ---- wave scan of thread aggregates -> block-local exclusive prefix ---
    Pair w; w.a = ta[EPT - 1]; w.b = tb[EPT - 1];
    #pragma unroll
    for (int off = 1; off < 64; off <<= 1) {
        Pair u; u.a = __shfl_up(w.a, off); u.b = __shfl_up(w.b, off);
        if (lane >= off) w = compose(u, w);
    }
    if (lane == 63) wS[wid] = w;
    __syncthreads();
    Pair wpre = ident();
    #pragma unroll
    for (int i = 0; i < TPB / 64; ++i) if (i < wid) wpre = compose(wpre, wS[i]);
    Pair up; up.a = __shfl_up(w.a, 1); up.b = __shfl_up(w.b, 1);
    Pair ex = (lane == 0) ? wpre : compose(wpre, up);

    // ---- publish aggregate ASAP, then shallow lookback (thread 0) ---------
    if (tid == 0) {
        Pair bagg = wS[0];
        #pragma unroll
        for (int i = 1; i < TPB / 64; ++i) bagg = compose(bagg, wS[i]);
        __hip_atomic_store(agg_a + vid, bagg.a, __ATOMIC_RELAXED, __HIP_MEMORY_SCOPE_AGENT);
        __hip_atomic_store(agg_b + vid, bagg.b, __ATOMIC_RELAXED, __HIP_MEMORY_SCOPE_AGENT);
        __hip_atomic_store(flags + vid, 1, __ATOMIC_RELEASE, __HIP_MEMORY_SCOPE_AGENT);

        // suffix composition of predecessor aggregates; width-0 absorbs.
        // terminates at block 0 (width-0: element 0 is the constant p0).
        Pair P = ident();
        int j = vid - 1;
        while (j >= 0) {
            while (__hip_atomic_load(flags + j, __ATOMIC_ACQUIRE,
                                     __HIP_MEMORY_SCOPE_AGENT) == 0)
                __builtin_amdgcn_s_sleep(1);
            Pair r;
            r.a = __hip_atomic_load(agg_a + j, __ATOMIC_RELAXED, __HIP_MEMORY_SCOPE_AGENT);
            r.b = __hip_atomic_load(agg_b + j, __ATOMIC_RELAXED, __HIP_MEMORY_SCOPE_AGENT);
            P = compose(r, P);
            if (P.a == P.b) break;
            --j;
        }
        sY = med3f(0.0f, P.a, P.b);   // vid 0: med3(0,-inf,+inf) = 0, inert
    }
    __syncthreads();

    // ---- apply: value-threading (1 med3/elem), coalesced transpose store --
    const float ytin = med3f(sY, ex.a, ex.b);    // exact incoming value
    if (blockFull) {
        #pragma unroll
        for (int j = 0; j < EPT; ++j)
            xpose[j * LPAD + tid] = med3f(ytin, ta[j], tb[j]);
        __syncthreads();
        #pragma unroll
        for (int c4 = 0; c4 < EPT / 4; ++c4) {
            const int q4    = c4 * (TPB * 4) + 4 * tid;  // elem idx in tile
            const int owner = q4 >> 4;                   // producing thread
            const int slot  = q4 & 15;                   // j within thread
            float4 f;
            f.x = xpose[(slot + 0) * LPAD + owner];
            f.y = xpose[(slot + 1) * LPAD + owner];
            f.z = xpose[(slot + 2) * LPAD + owner];
            f.w = xpose[(slot + 3) * LPAD + owner];
            reinterpret_cast<float4*>(out + tile0)[c4 * TPB + tid] = f;
        }
    } else {
        #pragma unroll
        for (int j = 0; j < EPT; ++j)
            if (base + j < n) out[base + j] = med3f(ytin, ta[j], tb[j]);
    }
}

// ========================== host launcher ==================================
extern "C" void kernel_launch(void* const* d_in, const int* in_sizes, int n_in,
                              void* d_out, int out_size, void* d_ws, size_t ws_size,
                              hipStream_t stream) {
    const float* in   = (const float*)d_in[0];   // [T+1], in[0] = p0
    const float* kptr = (const float*)d_in[1];   // scalar weight
    float* out = (float*)d_out;                  // [T+1]
    const int n  = in_sizes[0];
    const int nb = (n + EPB - 1) / EPB;          // 4097 for T = 2^24

    char* ws     = (char*)d_ws;
    int* counter = (int*)ws;                     // 64-byte slot
    int* flags   = (int*)(ws + 64);              // nb ints
    size_t off   = 64 + (((size_t)nb * 4 + 63) & ~(size_t)63);
    float* agg_a = (float*)(ws + off);
    float* agg_b = agg_a + nb;

    // zero counter + flags each call (graph-capture-safe async memset)
    (void)hipMemsetAsync(d_ws, 0, 64 + (size_t)nb * 4, stream);
    k_fused<<<nb, TPB, 0, stream>>>(in, kptr, counter, flags,
                                    agg_a, agg_b, out, n);
}

// Round 11
// 72.598 us; speedup vs baseline: 2.4528x; 2.4528x over previous
//
#include <hip/hip_runtime.h>
#include <math.h>

// y_t = clamp(y_{t-1}, x_t, x_t+1): play operator as associative clamp-scan.
// compose(l, r) = "apply l first, then r". min/max/med3-only => exact =>
// any regrouping is bit-identical (deterministic).
//
// COLLAPSE PROPERTY: composed windows contract; width-0 is absorbing and
// block 0's aggregate is width-0 (elem 0 = constant p0). So a block needs
// only predecessor AGGREGATES: walk back composing until the suffix
// collapses (typ. depth ~1).
//
// SYNC: relaxed-only atomics. Agent-scope acquire/release on gfx950 do bulk
// L2 writeback/invalidate (per-XCD L2s are non-coherent) -- measured 6x
// slowdown in rounds 2/10. Instead the 64-bit polled word IS the payload:
// packed (a,b) floats, sentinel = all-ones (NaN:NaN, unreachable since
// aggregates are finite). Relaxed atomics bypass caches for that word only.

#define TPB 256
#define EPT 16
#define EPB (TPB * EPT)   // 4096 elements per block -> nb = 4097 for T=2^24
#define XP 17             // LDS transpose pitch (words), owner-major

typedef unsigned long long u64;
#define SENT 0xFFFFFFFFFFFFFFFFull

struct Pair { float a, b; };
union PackU { float2 f; u64 u; };

__device__ __forceinline__ float med3f(float x, float lo, float hi) {
    return __builtin_amdgcn_fmed3f(x, lo, hi);   // clamp(x, lo, hi), lo<=hi
}
__device__ __forceinline__ Pair compose(Pair l, Pair r) {
    Pair o; o.a = med3f(l.a, r.a, r.b); o.b = med3f(l.b, r.a, r.b); return o;
}
__device__ __forceinline__ Pair ident() {
    Pair p; p.a = -INFINITY; p.b = INFINITY; return p;
}

__global__ __launch_bounds__(TPB)
void k_fused(const float* __restrict__ in, const float* __restrict__ kptr,
             int* counter, u64* agg, float* __restrict__ out, int n) {
    __shared__ int   svid;
    __shared__ Pair  wS[TPB / 64];
    __shared__ float sY;
    __shared__ float xpose[TPB * XP];

    // dynamic block id in dispatch-start order (lookback forward progress)
    if (threadIdx.x == 0)
        svid = __hip_atomic_fetch_add(counter, 1, __ATOMIC_RELAXED,
                                      __HIP_MEMORY_SCOPE_AGENT);
    __syncthreads();
    const int vid  = svid;
    const int tid  = threadIdx.x, lane = tid & 63, wid = tid >> 6;
    const int tile0 = vid * EPB;
    const int base  = tile0 + tid * EPT;
    const float k   = kptr[0];
    const bool blockFull = (tile0 + EPB <= n);   // uniform across block

    // ---- local chain: per-element thread-local inclusive windows ----------
    float ta[EPT], tb[EPT];                      // static indexing only
    {
        float a = -INFINITY, b = INFINITY;
        if (blockFull) {
            #pragma unroll
            for (int v = 0; v < EPT / 4; ++v) {
                float4 f = reinterpret_cast<const float4*>(in + base)[v];
                float xv[4] = {f.x, f.y, f.z, f.w};
                #pragma unroll
                for (int jj = 0; jj < 4; ++jj) {
                    float lo = xv[jj] * k, hi = lo + 1.0f;
                    if (v == 0 && jj == 0 && base == 0) { lo = xv[0]; hi = xv[0]; }
                    a = med3f(a, lo, hi);
                    b = med3f(b, lo, hi);
                    ta[4*v+jj] = a; tb[4*v+jj] = b;
                }
            }
        } else {
            #pragma unroll
            for (int j = 0; j < EPT; ++j) {
                if (base + j < n) {
                    float x = in[base + j];
                    float lo = x * k, hi = lo + 1.0f;
                    if (j == 0 && base == 0) { lo = x; hi = x; }
                    a = med3f(a, lo, hi);
                    b = med3f(b, lo, hi);
                }
                ta[j] = a; tb[j] = b;
            }
        }
    }

    // ---- wave scan of thread aggregates -> block-local exclusive prefix ---
    Pair w; w.a = ta[EPT - 1]; w.b = tb[EPT - 1];
    #pragma unroll
    for (int off = 1; off < 64; off <<= 1) {
        Pair u; u.a = __shfl_up(w.a, off); u.b = __shfl_up(w.b, off);
        if (lane >= off) w = compose(u, w);
    }
    if (lane == 63) wS[wid] = w;
    __syncthreads();
    Pair wpre = ident();
    #pragma unroll
    for (int i = 0; i < TPB / 64; ++i) if (i < wid) wpre = compose(wpre, wS[i]);
    Pair up; up.a = __shfl_up(w.a, 1); up.b = __shfl_up(w.b, 1);
    Pair ex = (lane == 0) ? wpre : compose(wpre, up);

    // ---- publish aggregate (payload = sync word), shallow lookback --------
    if (tid == 0) {
        Pair bagg = wS[0];
        #pragma unroll
        for (int i = 1; i < TPB / 64; ++i) bagg = compose(bagg, wS[i]);
        PackU pk; pk.f = make_float2(bagg.a, bagg.b);   // finite -> != SENT
        __hip_atomic_store(agg + vid, pk.u, __ATOMIC_RELAXED,
                           __HIP_MEMORY_SCOPE_AGENT);

        // suffix composition of predecessor aggregates; width-0 absorbs.
        // terminates at block 0 (width-0: elem 0 is the constant p0).
        Pair P = ident();
        int j = vid - 1;
        while (j >= 0) {
            PackU v;
            for (;;) {
                v.u = __hip_atomic_load(agg + j, __ATOMIC_RELAXED,
                                        __HIP_MEMORY_SCOPE_AGENT);
                if (v.u != SENT) break;
                __builtin_amdgcn_s_sleep(2);
            }
            Pair r; r.a = v.f.x; r.b = v.f.y;
            P = compose(r, P);
            if (P.a == P.b) break;
            --j;
        }
        sY = med3f(0.0f, P.a, P.b);   // vid 0: med3(0,-inf,+inf)=0, inert
    }
    __syncthreads();

    // ---- apply: value-threading (1 med3/elem), coalesced transpose store --
    const float ytin = med3f(sY, ex.a, ex.b);    // exact incoming value
    if (blockFull) {
        #pragma unroll
        for (int j = 0; j < EPT; ++j)            // owner-major, pitch 17:
            xpose[tid * XP + j] = med3f(ytin, ta[j], tb[j]);  // 17 odd ->
        __syncthreads();                         // <=2-way on both sides
        #pragma unroll
        for (int c4 = 0; c4 < EPT / 4; ++c4) {
            const int q4    = c4 * (TPB * 4) + 4 * tid;  // elem idx in tile
            const int owner = q4 >> 4;                   // producing thread
            const int slot  = q4 & 15;                   // j within thread
            float4 f;
            f.x = xpose[owner * XP + slot + 0];
            f.y = xpose[owner * XP + slot + 1];
            f.z = xpose[owner * XP + slot + 2];
            f.w = xpose[owner * XP + slot + 3];
            reinterpret_cast<float4*>(out + tile0)[c4 * TPB + tid] = f;
        }
    } else {
        #pragma unroll
        for (int j = 0; j < EPT; ++j)
            if (base + j < n) out[base + j] = med3f(ytin, ta[j], tb[j]);
    }
}

// ========================== host launcher ==================================
extern "C" void kernel_launch(void* const* d_in, const int* in_sizes, int n_in,
                              void* d_out, int out_size, void* d_ws, size_t ws_size,
                              hipStream_t stream) {
    const float* in   = (const float*)d_in[0];   // [T+1], in[0] = p0
    const float* kptr = (const float*)d_in[1];   // scalar weight
    float* out = (float*)d_out;                  // [T+1]
    const int n  = in_sizes[0];
    const int nb = (n + EPB - 1) / EPB;          // 4097 for T = 2^24

    char* ws     = (char*)d_ws;
    int*  counter = (int*)ws;                    // 64-byte slot, zeroed
    u64*  agg     = (u64*)(ws + 64);             // nb packed aggregates

    (void)hipMemsetAsync(ws, 0, 64, stream);                 // counter = 0
    (void)hipMemsetAsync(ws + 64, 0xFF, (size_t)nb * 8, stream);  // SENT
    k_fused<<<nb, TPB, 0, stream>>>(in, kptr, counter, agg, out, n);
}

// Round 12
// 26.406 us; speedup vs baseline: 6.7437x; 2.7493x over previous
//
#include <hip/hip_runtime.h>
#include <math.h>

// y_t = clamp(y_{t-1}, x_t, x_t+1): play operator as associative clamp-scan.
// compose(l, r) = "apply l first, then r". min/max/med3-only => exact =>
// any regrouping is bit-identical (deterministic).
//
// COLLAPSE PROPERTY: composed windows contract and width-0 is absorbing.
// Element 0's window is (p0,p0) -- width 0 -- so the composition of ANY
// prefix that reaches element 0 is collapsed. Therefore each block can
// recompute its exact incoming value from the RAW INPUT alone: walk
// backwards from its tile in 256-element chunks, composing chunk aggregates
// until the suffix collapses (guaranteed by element 0; typically 1 chunk for
// this data). NO inter-block communication: rounds 2/10/11 measured that
// cross-XCD sync through non-coherent L2s costs 2-6x (acq/rel = bulk L2
// writeback/invalidate; even relaxed cache-bypass polling stalls the grid).
// One kernel, no atomics, no workspace: read 64 MB once, write 64 MB once.

#define TPB 256
#define EPT 16
#define EPB (TPB * EPT)   // 4096 elements per block -> nb = 4097 for T=2^24
#define XP 17             // LDS transpose pitch (words), owner-major
#define HCH 256           // halo chunk size (1 element per thread)

struct Pair { float a, b; };

__device__ __forceinline__ float med3f(float x, float lo, float hi) {
    return __builtin_amdgcn_fmed3f(x, lo, hi);   // clamp(x, lo, hi), lo<=hi
}
__device__ __forceinline__ Pair compose(Pair l, Pair r) {
    Pair o; o.a = med3f(l.a, r.a, r.b); o.b = med3f(l.b, r.a, r.b); return o;
}
__device__ __forceinline__ Pair ident() {
    Pair p; p.a = -INFINITY; p.b = INFINITY; return p;
}

__global__ __launch_bounds__(TPB)
void k_scan(const float* __restrict__ in, const float* __restrict__ kptr,
            float* __restrict__ out, int n) {
    const int tid  = threadIdx.x, lane = tid & 63, wid = tid >> 6;
    const int vid  = blockIdx.x;
    const int tile0 = vid * EPB;
    const int base  = tile0 + tid * EPT;
    const float k   = kptr[0];
    const bool blockFull = (tile0 + EPB <= n);   // uniform across block

    __shared__ Pair  wS[TPB / 64];               // block-scan wave aggs
    __shared__ Pair  wC[TPB / 64];               // halo-chunk wave aggs
    __shared__ float xpose[TPB * XP];            // transpose store buffer

    // ---- 1) tile load + per-element thread-local inclusive windows --------
    float ta[EPT], tb[EPT];                      // static indexing only
    {
        float a = -INFINITY, b = INFINITY;
        if (blockFull) {
            #pragma unroll
            for (int v = 0; v < EPT / 4; ++v) {
                float4 f = reinterpret_cast<const float4*>(in + base)[v];
                float xv[4] = {f.x, f.y, f.z, f.w};
                #pragma unroll
                for (int jj = 0; jj < 4; ++jj) {
                    float lo = xv[jj] * k, hi = lo + 1.0f;
                    if (v == 0 && jj == 0 && base == 0) { lo = xv[0]; hi = xv[0]; }
                    a = med3f(a, lo, hi);
                    b = med3f(b, lo, hi);
                    ta[4*v+jj] = a; tb[4*v+jj] = b;
                }
            }
        } else {
            #pragma unroll
            for (int j = 0; j < EPT; ++j) {
                if (base + j < n) {
                    float x = in[base + j];
                    float lo = x * k, hi = lo + 1.0f;
                    if (j == 0 && base == 0) { lo = x; hi = x; }
                    a = med3f(a, lo, hi);
                    b = med3f(b, lo, hi);
                }
                ta[j] = a; tb[j] = b;
            }
        }
    }

    // ---- 2) block scan of thread aggregates -> per-thread exclusive ex ----
    Pair w; w.a = ta[EPT - 1]; w.b = tb[EPT - 1];
    #pragma unroll
    for (int off = 1; off < 64; off <<= 1) {
        Pair u; u.a = __shfl_up(w.a, off); u.b = __shfl_up(w.b, off);
        if (lane >= off) w = compose(u, w);
    }
    if (lane == 63) wS[wid] = w;
    __syncthreads();
    Pair wpre = ident();
    #pragma unroll
    for (int i = 0; i < TPB / 64; ++i) if (i < wid) wpre = compose(wpre, wS[i]);
    Pair up; up.a = __shfl_up(w.a, 1); up.b = __shfl_up(w.b, 1);
    Pair ex = (lane == 0) ? wpre : compose(wpre, up);

    // ---- 3) halo backward walk: exact incoming value, no communication ----
    // S = composition of elements [chunkStart, tile0); prepend older chunks
    // until S collapses (a==b). Guaranteed at element 0 (constant p0).
    Pair S = ident();
    int chunkEnd = tile0;
    while (chunkEnd > 0) {
        int chunkStart = chunkEnd - HCH; if (chunkStart < 0) chunkStart = 0;
        const int count = chunkEnd - chunkStart;
        const int e = chunkStart + tid;
        Pair wnd = ident();
        if (tid < count) {                       // padding at the NEW end is
            float x = in[e];                     // ident -> order preserved
            float lo = x * k, hi = lo + 1.0f;
            if (e == 0) { lo = x; hi = x; }      // constant p0
            wnd.a = lo; wnd.b = hi;
        }
        // ordered wave tree-reduce; lane 0 = wave aggregate (ascending order)
        #pragma unroll
        for (int off = 1; off < 64; off <<= 1) {
            Pair u; u.a = __shfl_down(wnd.a, off); u.b = __shfl_down(wnd.b, off);
            Pair c = compose(wnd, u);
            if (lane + off < 64) wnd = c;
        }
        if (lane == 0) wC[wid] = wnd;
        __syncthreads();
        Pair cagg = wC[0];
        #pragma unroll
        for (int i = 1; i < TPB / 64; ++i) cagg = compose(cagg, wC[i]);
        __syncthreads();                         // protect wC for next iter
        S = compose(cagg, S);                    // prepend older chunk
        if (S.a == S.b) break;                   // collapsed: exact
        chunkEnd = chunkStart;
    }
    const float ysrc = med3f(0.0f, S.a, S.b);    // collapsed (or vid 0: inert)

    // ---- 4) apply: value-threading (1 med3/elem), coalesced store ---------
    const float ytin = med3f(ysrc, ex.a, ex.b);  // exact incoming value
    if (blockFull) {
        #pragma unroll
        for (int j = 0; j < EPT; ++j)            // owner-major, pitch 17
            xpose[tid * XP + j] = med3f(ytin, ta[j], tb[j]);
        __syncthreads();
        #pragma unroll
        for (int c4 = 0; c4 < EPT / 4; ++c4) {
            const int q4    = c4 * (TPB * 4) + 4 * tid;  // elem idx in tile
            const int owner = q4 >> 4;                   // producing thread
            const int slot  = q4 & 15;                   // j within thread
            float4 f;
            f.x = xpose[owner * XP + slot + 0];
            f.y = xpose[owner * XP + slot + 1];
            f.z = xpose[owner * XP + slot + 2];
            f.w = xpose[owner * XP + slot + 3];
            reinterpret_cast<float4*>(out + tile0)[c4 * TPB + tid] = f;
        }
    } else {
        #pragma unroll
        for (int j = 0; j < EPT; ++j)
            if (base + j < n) out[base + j] = med3f(ytin, ta[j], tb[j]);
    }
}

// ========================== host launcher ==================================
extern "C" void kernel_launch(void* const* d_in, const int* in_sizes, int n_in,
                              void* d_out, int out_size, void* d_ws, size_t ws_size,
                              hipStream_t stream) {
    const float* in   = (const float*)d_in[0];   // [T+1], in[0] = p0
    const float* kptr = (const float*)d_in[1];   // scalar weight
    float* out = (float*)d_out;                  // [T+1]
    const int n  = in_sizes[0];
    const int nb = (n + EPB - 1) / EPB;          // 4097 for T = 2^24

    k_scan<<<nb, TPB, 0, stream>>>(in, kptr, out, n);
}